// Round 4
// baseline (173.801 us; speedup 1.0000x reference)
//
#include <hip/hip_runtime.h>
#include <stdint.h>

// GRU: B=4096, T=128, I=16, H=64. Gate order r,z,n (PyTorch).
// v3: 8 waves/block (512 thr), 256 blocks (1/CU) -> 2 waves/SIMD for
// MFMA/VALU/latency overlap (m114). Wave pair (w, w+4) owns hidden cols
// [16w,16w+16): wave w does K=0..31 of the h-GEMM (9 MFMAs), wave w+4 does
// K=32..63 + x-tile (12 MFMAs, biases in acc-init). Partial accs exchanged
// via stride-20 LDS planes (2-way banks = free), then each wave finalizes
// gates for 2 rows (w: rows 0-7, w+4: rows 8-15). Split-bf16 (hi*hi + lo*hi
// + hi*lo) keeps near-fp32 accuracy. exp-scales pre-folded into weights.

#define T_STEPS 128
#define NI 16
#define NH 64
#define RB 16
#define S_EX 20                 // exchange row stride in floats (2-way banks)
#define PLANE (16 * S_EX)       // floats per (khalf,acc) plane

typedef float    f32x4  __attribute__((ext_vector_type(4)));
typedef uint32_t u32x4  __attribute__((ext_vector_type(4)));
typedef short    bf16x8 __attribute__((ext_vector_type(8)));  // MFMA operand
typedef __bf16   bfv8   __attribute__((ext_vector_type(8)));

static constexpr float LOG2E = 1.4426950408889634f;

static __device__ __forceinline__ uint32_t fbits(float f) { return __builtin_bit_cast(uint32_t, f); }
static __device__ __forceinline__ float    bitsf(uint32_t u) { return __builtin_bit_cast(float, u); }

// byte offset inside a [16 rows][64 cols] bf16 region (128B rows),
// 16B-chunk XOR swizzle by row so strided frag reads are 2-way (free).
static __device__ __forceinline__ int h_addr(int row, int col) {
  return row * 128 + (((col >> 3) ^ (row & 7)) << 4) + ((col & 7) << 1);
}

static __device__ __forceinline__ bf16x8 ld_frag16(const unsigned char* p) {
  u32x4 v = *(const u32x4*)p;                           // ds_read_b128
  return __builtin_bit_cast(bf16x8, v);
}

#define MFMA(acc, a, b) acc = __builtin_amdgcn_mfma_f32_16x16x32_bf16(a, b, acc, 0, 0, 0)

__global__ __launch_bounds__(512)
void gru_fused(const float* __restrict__ x,
               const float* __restrict__ w_ih,
               const float* __restrict__ w_hh,
               const float* __restrict__ b_ih,
               const float* __restrict__ b_hh,
               const float* __restrict__ fc_w,
               const float* __restrict__ fc_b,
               float* __restrict__ out)
{
  __shared__ __align__(16) unsigned char sH[2][2048];   // [hi/lo][16x64 bf16]
  __shared__ __align__(16) float sEx[4][8][PLANE];      // [pair][khalf*4+acc]
  __shared__ float s_red[8][8];

  const int tid  = threadIdx.x;
  const int lane = tid & 63;
  const int wv   = tid >> 6;      // 0..7
  const int pair = wv & 3;        // hidden-col group
  const int kh   = wv >> 2;       // 0: K 0..31 ("A"), 1: K 32..63 + x ("B")
  const int colg = lane & 15;
  const int grp  = lane >> 4;
  const int rb   = blockIdx.x * RB;
  const int hc   = pair * 16 + colg;   // hidden col 0..63

  // zero h buffer (h0 = 0): 4096 B, 512 threads x 2 u32
  ((uint32_t*)sH)[tid]       = 0u;
  ((uint32_t*)sH)[tid + 512] = 0u;

  // ---- weight B-fragments (own K-half only), pre-scaled by exp factors ----
  // B-frag: lane (grp,colg) holds B[k][n], n = hc, k = kh*32 + grp*8 + j.
  const float scl0 = -LOG2E, scl2 = 2.0f * LOG2E;
  bf16x8 bhi[3], blo[3];
  #pragma unroll
  for (int g = 0; g < 3; ++g) {
    const float s = (g == 2) ? scl2 : scl0;
    const float* wr = w_hh + (size_t)(g * 64 + hc) * NH + kh * 32 + grp * 8;
    bfv8 vhi, vlo;
    #pragma unroll
    for (int j = 0; j < 8; ++j) {
      float w = wr[j] * s;
      __bf16 hi = (__bf16)w;
      vhi[j] = hi;
      vlo[j] = (__bf16)(w - (float)hi);
    }
    bhi[g] = __builtin_bit_cast(bf16x8, vhi);
    blo[g] = __builtin_bit_cast(bf16x8, vlo);
  }
  bf16x8 bx[3];
  if (kh) {
    #pragma unroll
    for (int g = 0; g < 3; ++g) {
      const float s = (g == 2) ? scl2 : scl0;
      const float* wi = w_ih + (size_t)(g * 64 + hc) * NI + (grp & 1) * 8;
      bfv8 vx;
      #pragma unroll
      for (int j = 0; j < 8; ++j) vx[j] = (__bf16)(wi[j] * s);
      bx[g] = __builtin_bit_cast(bf16x8, vx);
    }
  }

  // biases folded into B-wave acc init (pre-scaled)
  const float biasR  = kh ? scl0 * (b_ih[hc] + b_hh[hc])           : 0.f;
  const float biasZ  = kh ? scl0 * (b_ih[64 + hc] + b_hh[64 + hc]) : 0.f;
  const float biasNh = kh ? scl2 * b_hh[128 + hc]                  : 0.f;
  const float biasNx = kh ? scl2 * b_ih[128 + hc]                  : 0.f;

  // ---- hoisted LDS addresses (all t-invariant) ----
  const int a_hi = h_addr(colg, kh * 32 + grp * 8);
  const int a_lo = 2048 + a_hi;
  const int wo0  = h_addr(kh * 8 + 2 * grp + 0, hc);   // gate-phase h writes
  const int wo1  = h_addr(kh * 8 + 2 * grp + 1, hc);
  float* exW = &sEx[pair][kh * 4][(4 * grp) * S_EX + colg];        // producer
  const float* exR = &sEx[pair][0][(kh * 8 + 2 * grp) * S_EX + colg]; // consumer

  float hold0 = 0.f, hold1 = 0.f;   // fp32 master h for this lane's 2 rows

  const float* xp = x + (size_t)(rb + colg) * T_STEPS * NI + (grp & 1) * 8;
  f32x4 xa = {0.f,0.f,0.f,0.f}, xb = {0.f,0.f,0.f,0.f};
  if (kh) { xa = *(const f32x4*)xp; xb = *(const f32x4*)(xp + 4); }
  const bool hi_grp = (grp < 2);

  __syncthreads();

  for (int t = 0; t < T_STEPS; ++t) {
    // A-fragments of h (own K-half) — issue first
    bf16x8 ah = ld_frag16((const unsigned char*)sH + a_hi);
    bf16x8 al = ld_frag16((const unsigned char*)sH + a_lo);

    f32x4 aR  = {biasR,  biasR,  biasR,  biasR};
    f32x4 aZ  = {biasZ,  biasZ,  biasZ,  biasZ};
    f32x4 aNh = {biasNh, biasNh, biasNh, biasNh};
    f32x4 aNx = {biasNx, biasNx, biasNx, biasNx};

    bf16x8 ax;
    f32x4 xna = xa, xnb = xb;
    if (kh) {
      // build split-bf16 x fragment: grp 0,1 carry trunc-hi(x); 2,3 residual
      uint32_t d0, d1, d2, d3;
      {
        float v[8];
        #pragma unroll
        for (int j = 0; j < 4; ++j) {
          float x0 = xa[j], x1 = xb[j];
          float b0 = bitsf(fbits(x0) & 0xffff0000u);
          float b1 = bitsf(fbits(x1) & 0xffff0000u);
          v[j]     = hi_grp ? x0 : (x0 - b0);
          v[4 + j] = hi_grp ? x1 : (x1 - b1);
        }
        d0 = __builtin_amdgcn_perm(fbits(v[1]), fbits(v[0]), 0x07060302u);
        d1 = __builtin_amdgcn_perm(fbits(v[3]), fbits(v[2]), 0x07060302u);
        d2 = __builtin_amdgcn_perm(fbits(v[5]), fbits(v[4]), 0x07060302u);
        d3 = __builtin_amdgcn_perm(fbits(v[7]), fbits(v[6]), 0x07060302u);
      }
      u32x4 axu = {d0, d1, d2, d3};
      ax = __builtin_bit_cast(bf16x8, axu);
      // prefetch next step's x
      const int tn = (t < T_STEPS - 1) ? (t + 1) : t;
      xna = *(const f32x4*)(xp + (size_t)tn * NI);
      xnb = *(const f32x4*)(xp + (size_t)tn * NI + 4);
    }

    // h-GEMM partials, split-bf16 (this wave's K-half)
    MFMA(aR,  ah, bhi[0]); MFMA(aR,  al, bhi[0]); MFMA(aR,  ah, blo[0]);
    MFMA(aZ,  ah, bhi[1]); MFMA(aZ,  al, bhi[1]); MFMA(aZ,  ah, blo[1]);
    MFMA(aNh, ah, bhi[2]); MFMA(aNh, al, bhi[2]); MFMA(aNh, ah, blo[2]);
    if (kh) {
      MFMA(aR,  ax, bx[0]);
      MFMA(aZ,  ax, bx[1]);
      MFMA(aNx, ax, bx[2]);
    }

    // write partials to exchange planes (2-way banks)
    #pragma unroll
    for (int q = 0; q < 4; ++q) {
      exW[q * S_EX + 0 * PLANE] = aR[q];
      exW[q * S_EX + 1 * PLANE] = aZ[q];
      exW[q * S_EX + 2 * PLANE] = aNh[q];
    }
    if (kh) {
      #pragma unroll
      for (int q = 0; q < 4; ++q) exW[q * S_EX + 3 * PLANE] = aNx[q];
    }
    __syncthreads();

    // consumer: finalize gates for this lane's 2 rows (kh*8 + 2*grp + q')
    {
      float sRv = exR[0 * S_EX + 0 * PLANE] + exR[0 * S_EX + 4 * PLANE];
      float sZv = exR[0 * S_EX + 1 * PLANE] + exR[0 * S_EX + 5 * PLANE];
      float sNh = exR[0 * S_EX + 2 * PLANE] + exR[0 * S_EX + 6 * PLANE];
      float sNx = exR[0 * S_EX + 7 * PLANE];
      float r = __builtin_amdgcn_rcpf(1.0f + __builtin_amdgcn_exp2f(sRv));
      float z = __builtin_amdgcn_rcpf(1.0f + __builtin_amdgcn_exp2f(sZv));
      float tv = fmaf(r, sNh, sNx);
      float n = fmaf(-2.0f, __builtin_amdgcn_rcpf(__builtin_amdgcn_exp2f(tv) + 1.0f), 1.0f);
      float h = n + z * (hold0 - n);
      hold0 = h;
      uint32_t u = fbits(h);
      float hif = bitsf(u & 0xffff0000u);
      *(uint16_t*)((unsigned char*)sH + wo0)        = (uint16_t)(u >> 16);
      *(uint16_t*)((unsigned char*)sH + 2048 + wo0) = (uint16_t)(fbits(h - hif) >> 16);
    }
    {
      float sRv = exR[1 * S_EX + 0 * PLANE] + exR[1 * S_EX + 4 * PLANE];
      float sZv = exR[1 * S_EX + 1 * PLANE] + exR[1 * S_EX + 5 * PLANE];
      float sNh = exR[1 * S_EX + 2 * PLANE] + exR[1 * S_EX + 6 * PLANE];
      float sNx = exR[1 * S_EX + 7 * PLANE];
      float r = __builtin_amdgcn_rcpf(1.0f + __builtin_amdgcn_exp2f(sRv));
      float z = __builtin_amdgcn_rcpf(1.0f + __builtin_amdgcn_exp2f(sZv));
      float tv = fmaf(r, sNh, sNx);
      float n = fmaf(-2.0f, __builtin_amdgcn_rcpf(__builtin_amdgcn_exp2f(tv) + 1.0f), 1.0f);
      float h = n + z * (hold1 - n);
      hold1 = h;
      uint32_t u = fbits(h);
      float hif = bitsf(u & 0xffff0000u);
      *(uint16_t*)((unsigned char*)sH + wo1)        = (uint16_t)(u >> 16);
      *(uint16_t*)((unsigned char*)sH + 2048 + wo1) = (uint16_t)(fbits(h - hif) >> 16);
    }
    __syncthreads();   // h(t+1) ready; exchange planes free for reuse
    xa = xna; xb = xnb;
  }

  // ---- head: out[b] = sum_col h[b][col]*fc_w[col] + fc_b ----
  float fw = fc_w[hc];
  float v0 = hold0 * fw, v1 = hold1 * fw;
  #pragma unroll
  for (int off = 1; off < 16; off <<= 1) {     // reduce over 16 cols in grp
    v0 += __shfl_xor(v0, off, 64);
    v1 += __shfl_xor(v1, off, 64);
  }
  if (colg == 0) {
    s_red[wv][2 * grp + 0] = v0;
    s_red[wv][2 * grp + 1] = v1;
  }
  __syncthreads();
  if (tid < 16) {
    float s = fc_b[0];
    if (tid < 8) {
      s += s_red[0][tid] + s_red[1][tid] + s_red[2][tid] + s_red[3][tid];
    } else {
      int r2 = tid - 8;
      s += s_red[4][r2] + s_red[5][r2] + s_red[6][r2] + s_red[7][r2];
    }
    out[rb + tid] = s;
  }
}

extern "C" void kernel_launch(void* const* d_in, const int* in_sizes, int n_in,
                              void* d_out, int out_size, void* d_ws, size_t ws_size,
                              hipStream_t stream) {
  (void)in_sizes; (void)n_in; (void)d_ws; (void)ws_size;
  const float* x    = (const float*)d_in[0];
  const float* w_ih = (const float*)d_in[1];
  const float* w_hh = (const float*)d_in[2];
  const float* b_ih = (const float*)d_in[3];
  const float* b_hh = (const float*)d_in[4];
  const float* fc_w = (const float*)d_in[5];
  const float* fc_b = (const float*)d_in[6];
  float* out = (float*)d_out;
  const int nblocks = out_size / RB;  // 256 blocks, 1 per CU
  gru_fused<<<dim3(nblocks), dim3(512), 0, stream>>>(x, w_ih, w_hh, b_ih, b_hh,
                                                     fc_w, fc_b, out);
}